// Round 1
// baseline (296.147 us; speedup 1.0000x reference)
//
#include <hip/hip_runtime.h>
#include <math.h>

namespace {
constexpr int B = 4, N = 512, K = 128, C = 256, S = 2;
constexpr int H8 = 128, W8 = 128, P8 = H8 * W8;
constexpr int H16 = 64, W16 = 64, P16 = H16 * W16;
constexpr float EPS = 1e-12f;
constexpr int KCH = 16;           // k-samples per wave
constexpr int WPN = K / KCH;      // waves per (b,n)
}

// [B,C,P] -> [B,P,C] tiled transpose (64x64 tiles, 256 threads, LDS padded)
__global__ __launch_bounds__(256) void k_transpose(
    const float* __restrict__ in, float* __restrict__ out, int P)
{
    __shared__ float tile[64][65];
    const int b  = blockIdx.z;
    const int p0 = blockIdx.x * 64;
    const int c0 = blockIdx.y * 64;
    const int tid = threadIdx.x;
    const int tp = tid & 63, tq = tid >> 6;   // tq in 0..3
    const float* src = in + (size_t)b * C * P;
    float* dst = out + (size_t)b * P * C;
#pragma unroll
    for (int i = 0; i < 16; ++i) {
        const int cl = tq + i * 4;
        tile[cl][tp] = src[(size_t)(c0 + cl) * P + (p0 + tp)];
    }
    __syncthreads();
#pragma unroll
    for (int i = 0; i < 16; ++i) {
        const int pl = tq + i * 4;
        dst[(size_t)(p0 + pl) * C + (c0 + tp)] = tile[tp][pl];
    }
}

__global__ __launch_bounds__(256) void k_sample(
    const float* __restrict__ nodew,   // [B,N]
    const float* __restrict__ nodef,   // [B,N,C]
    const float* __restrict__ rel8,    // [B,P8]
    const float* __restrict__ rel16,   // [B,P16]
    const float* __restrict__ coords,  // [B,K,N,2]
    const float* __restrict__ ft8,     // [B,P8,C]
    const float* __restrict__ ft16,    // [B,P16,C]
    float* __restrict__ sims,          // [B,K,N,S]
    float* __restrict__ rels)          // [B,K,N,S]
{
    const int wave = blockIdx.x * 4 + (threadIdx.x >> 6);
    const int lane = threadIdx.x & 63;
    const int b  = wave / (N * WPN);
    const int rr = wave % (N * WPN);
    const int n  = rr / WPN;
    const int kc = rr % WPN;

    // node feature fragment (4 channels / lane) + its norm (computed once)
    const float4 nf = *reinterpret_cast<const float4*>(
        nodef + ((size_t)(b * N + n)) * C + lane * 4);
    float nn = nf.x * nf.x + nf.y * nf.y + nf.z * nf.z + nf.w * nf.w;
#pragma unroll
    for (int off = 32; off; off >>= 1) nn += __shfl_xor(nn, off);
    const float inv_nf = 1.0f / fmaxf(sqrtf(nn), EPS);
    const float wr = nodew[b * N + n];

    for (int kk = 0; kk < KCH; ++kk) {
        const int k = kc * KCH + kk;
        const float gx = coords[(((size_t)b * K + k) * N + n) * 2 + 0];
        const float gy = coords[(((size_t)b * K + k) * N + n) * 2 + 1];
#pragma unroll
        for (int s = 0; s < 2; ++s) {
            const int W_ = s ? W16 : W8;
            const int H_ = s ? H16 : H8;
            const float* __restrict__ relm =
                (s ? rel16 : rel8) + (size_t)b * (s ? P16 : P8);
            const float* __restrict__ ft =
                (s ? ft16 : ft8) + (size_t)b * (s ? P16 : P8) * C;

            const float ix = ((gx + 1.0f) * W_ - 1.0f) * 0.5f;
            const float iy = ((gy + 1.0f) * H_ - 1.0f) * 0.5f;
            const float x0f = floorf(ix), y0f = floorf(iy);
            const int x0 = (int)x0f, y0 = (int)y0f;
            const int x1 = x0 + 1, y1 = y0 + 1;
            const float fx1 = ix - x0f, fx0 = 1.0f - fx1;
            const float fy1 = iy - y0f, fy0 = 1.0f - fy1;
            const bool vx0 = (x0 >= 0) && (x0 < W_);
            const bool vx1 = (x1 >= 0) && (x1 < W_);
            const bool vy0 = (y0 >= 0) && (y0 < H_);
            const bool vy1 = (y1 >= 0) && (y1 < H_);
            float w00 = (vx0 && vy0) ? fx0 * fy0 : 0.0f;
            float w10 = (vx1 && vy0) ? fx1 * fy0 : 0.0f;
            float w01 = (vx0 && vy1) ? fx0 * fy1 : 0.0f;
            float w11 = (vx1 && vy1) ? fx1 * fy1 : 0.0f;
            const int cx0 = min(max(x0, 0), W_ - 1);
            const int cx1 = min(max(x1, 0), W_ - 1);
            const int cy0 = min(max(y0, 0), H_ - 1);
            const int cy1 = min(max(y1, 0), H_ - 1);
            const int p00 = cy0 * W_ + cx0, p10 = cy0 * W_ + cx1;
            const int p01 = cy1 * W_ + cx0, p11 = cy1 * W_ + cx1;

            const float4 f00 = *reinterpret_cast<const float4*>(ft + (size_t)p00 * C + lane * 4);
            const float4 f10 = *reinterpret_cast<const float4*>(ft + (size_t)p10 * C + lane * 4);
            const float4 f01 = *reinterpret_cast<const float4*>(ft + (size_t)p01 * C + lane * 4);
            const float4 f11 = *reinterpret_cast<const float4*>(ft + (size_t)p11 * C + lane * 4);

            const float sx = w00 * f00.x + w10 * f10.x + w01 * f01.x + w11 * f11.x;
            const float sy = w00 * f00.y + w10 * f10.y + w01 * f01.y + w11 * f11.y;
            const float sz = w00 * f00.z + w10 * f10.z + w01 * f01.z + w11 * f11.z;
            const float sw = w00 * f00.w + w10 * f10.w + w01 * f01.w + w11 * f11.w;

            float dot = nf.x * sx + nf.y * sy + nf.z * sz + nf.w * sw;
            float n2  = sx * sx + sy * sy + sz * sz + sw * sw;
#pragma unroll
            for (int off = 32; off; off >>= 1) {
                dot += __shfl_xor(dot, off);
                n2  += __shfl_xor(n2, off);
            }
            if (lane == 0) {
                const float sim = dot * inv_nf / fmaxf(sqrtf(n2), EPS);
                const float sr = w00 * relm[p00] + w10 * relm[p10]
                               + w01 * relm[p01] + w11 * relm[p11];
                const size_t o = (((size_t)b * K + k) * N + n) * S + s;
                sims[o] = sim;
                rels[o] = wr + sr;
            }
        }
    }
}

// per (b,k): softmax over N*S of rel, weighted sum of sim
__global__ __launch_bounds__(256) void k_logits(
    const float* __restrict__ sims, const float* __restrict__ rels,
    const float* __restrict__ lscale, float* __restrict__ logits)
{
    const int bk = blockIdx.x;
    const int tid = threadIdx.x;
    const int lane = tid & 63, wid = tid >> 6;
    const float* rp = rels + (size_t)bk * (N * S);
    const float* sp = sims + (size_t)bk * (N * S);
    __shared__ float red0[4], red1[4], red2[4];

    float m = -INFINITY;
    for (int i = tid; i < N * S; i += 256) m = fmaxf(m, rp[i]);
#pragma unroll
    for (int off = 32; off; off >>= 1) m = fmaxf(m, __shfl_xor(m, off));
    if (lane == 0) red0[wid] = m;
    __syncthreads();
    m = fmaxf(fmaxf(red0[0], red0[1]), fmaxf(red0[2], red0[3]));

    float se = 0.0f, ss = 0.0f;
    for (int i = tid; i < N * S; i += 256) {
        const float e = expf(rp[i] - m);
        se += e;
        ss += e * sp[i];
    }
#pragma unroll
    for (int off = 32; off; off >>= 1) {
        se += __shfl_xor(se, off);
        ss += __shfl_xor(ss, off);
    }
    if (lane == 0) { red1[wid] = se; red2[wid] = ss; }
    __syncthreads();
    if (tid == 0) {
        const float tse = red1[0] + red1[1] + red1[2] + red1[3];
        const float tss = red2[0] + red2[1] + red2[2] + red2[3];
        logits[bk] = (tss / tse) * expf(lscale[0]);
    }
}

// final softmax over K per b
__global__ __launch_bounds__(64) void k_out(
    const float* __restrict__ logits, float* __restrict__ out)
{
    const int b = blockIdx.x;
    const int lane = threadIdx.x;   // 64
    const float v0 = logits[b * K + lane];
    const float v1 = logits[b * K + lane + 64];
    float m = fmaxf(v0, v1);
#pragma unroll
    for (int off = 32; off; off >>= 1) m = fmaxf(m, __shfl_xor(m, off));
    const float e0 = expf(v0 - m), e1 = expf(v1 - m);
    float se = e0 + e1;
#pragma unroll
    for (int off = 32; off; off >>= 1) se += __shfl_xor(se, off);
    out[b * K + lane] = e0 / se;
    out[b * K + lane + 64] = e1 / se;
}

extern "C" void kernel_launch(void* const* d_in, const int* in_sizes, int n_in,
                              void* d_out, int out_size, void* d_ws, size_t ws_size,
                              hipStream_t stream)
{
    const float* nodew  = (const float*)d_in[0];
    const float* nodef  = (const float*)d_in[1];
    const float* rel8   = (const float*)d_in[2];
    const float* feat8  = (const float*)d_in[3];
    const float* rel16  = (const float*)d_in[4];
    const float* feat16 = (const float*)d_in[5];
    const float* coords = (const float*)d_in[6];
    const float* lscale = (const float*)d_in[7];

    float* ws     = (float*)d_ws;
    float* ft8    = ws;                                  // B*P8*C
    float* ft16   = ft8  + (size_t)B * P8 * C;           // B*P16*C
    float* sims   = ft16 + (size_t)B * P16 * C;          // B*K*N*S
    float* rels   = sims + (size_t)B * K * N * S;        // B*K*N*S
    float* logits = rels + (size_t)B * K * N * S;        // B*K
    float* out    = (float*)d_out;

    hipLaunchKernelGGL(k_transpose, dim3(P8 / 64, C / 64, B), dim3(256), 0, stream,
                       feat8, ft8, P8);
    hipLaunchKernelGGL(k_transpose, dim3(P16 / 64, C / 64, B), dim3(256), 0, stream,
                       feat16, ft16, P16);
    hipLaunchKernelGGL(k_sample, dim3(B * N * WPN / 4), dim3(256), 0, stream,
                       nodew, nodef, rel8, rel16, coords, ft8, ft16, sims, rels);
    hipLaunchKernelGGL(k_logits, dim3(B * K), dim3(256), 0, stream,
                       sims, rels, lscale, logits);
    hipLaunchKernelGGL(k_out, dim3(B), dim3(64), 0, stream, logits, out);
}

// Round 2
// 150.685 us; speedup vs baseline: 1.9653x; 1.9653x over previous
//
#include <hip/hip_runtime.h>
#include <hip/hip_fp16.h>
#include <math.h>

namespace {
constexpr int B = 4, N = 512, K = 128, C = 256, S = 2;
constexpr int H8 = 128, W8 = 128, P8 = H8 * W8;
constexpr int H16 = 64, W16 = 64, P16 = H16 * W16;
constexpr float EPS = 1e-12f;
constexpr int KCH = 8;            // k-samples per wave
constexpr int WPN = K / KCH;      // waves per (b,n)
}

// [B,C,P] fp32 -> [B,P,C] fp16 tiled transpose (64x64 tiles, 256 threads)
__global__ __launch_bounds__(256) void k_transpose(
    const float* __restrict__ in, __half* __restrict__ out, int P)
{
    __shared__ float tile[64][65];
    const int b  = blockIdx.z;
    const int p0 = blockIdx.x * 64;
    const int c0 = blockIdx.y * 64;
    const int tid = threadIdx.x;
    const int tp = tid & 63, tq = tid >> 6;   // tq in 0..3
    const float* src = in + (size_t)b * C * P;
    __half* dst = out + (size_t)b * P * C;
#pragma unroll
    for (int i = 0; i < 16; ++i) {
        const int cl = tq + i * 4;
        tile[cl][tp] = src[(size_t)(c0 + cl) * P + (p0 + tp)];
    }
    __syncthreads();
#pragma unroll
    for (int i = 0; i < 16; ++i) {
        const int pl = tq + i * 4;
        dst[(size_t)(p0 + pl) * C + (c0 + tp)] = __float2half(tile[tp][pl]);
    }
}

__device__ inline void h8_to_f(const float4 r, float* o)
{
    const __half2* h = reinterpret_cast<const __half2*>(&r);
#pragma unroll
    for (int i = 0; i < 4; ++i) {
        const float2 f = __half22float2(h[i]);
        o[2 * i] = f.x; o[2 * i + 1] = f.y;
    }
}

__global__ __launch_bounds__(256) void k_sample(
    const float* __restrict__ nodew,   // [B,N]
    const float* __restrict__ nodef,   // [B,N,C]
    const float* __restrict__ rel8,    // [B,P8]
    const float* __restrict__ rel16,   // [B,P16]
    const float* __restrict__ coords,  // [B,K,N,2]
    const __half* __restrict__ ft8,    // [B,P8,C]
    const __half* __restrict__ ft16,   // [B,P16,C]
    float* __restrict__ sims,          // [B,K,N,S]
    float* __restrict__ rels)          // [B,K,N,S]
{
    const int wave = blockIdx.x * 4 + (threadIdx.x >> 6);
    const int lane = threadIdx.x & 63;
    const int hf   = lane >> 5;        // 0: y0 row-pair, 1: y1 row-pair
    const int cg   = (lane & 31) * 8;  // 8 channels per lane
    const int b  = wave / (N * WPN);
    const int rr = wave % (N * WPN);
    const int n  = rr / WPN;
    const int kc = rr % WPN;

    // node feature fragment: 8 channels (lanes l and l+32 duplicate)
    float nf[8];
    {
        const float* np_ = nodef + ((size_t)(b * N + n)) * C + cg;
        const float4 a = *reinterpret_cast<const float4*>(np_);
        const float4 c4 = *reinterpret_cast<const float4*>(np_ + 4);
        nf[0]=a.x; nf[1]=a.y; nf[2]=a.z; nf[3]=a.w;
        nf[4]=c4.x; nf[5]=c4.y; nf[6]=c4.z; nf[7]=c4.w;
    }
    float nn = 0.0f;
#pragma unroll
    for (int c = 0; c < 8; ++c) nn += nf[c] * nf[c];
#pragma unroll
    for (int off = 32; off; off >>= 1) nn += __shfl_xor(nn, off);
    nn *= 0.5f;  // halves duplicate channels
    const float inv_nf = 1.0f / fmaxf(sqrtf(nn), EPS);
    const float wr = nodew[b * N + n];

    for (int kk = 0; kk < KCH; ++kk) {
        const int k = kc * KCH + kk;
        const float gx = coords[(((size_t)b * K + k) * N + n) * 2 + 0];
        const float gy = coords[(((size_t)b * K + k) * N + n) * 2 + 1];
#pragma unroll
        for (int s = 0; s < 2; ++s) {
            const int W_ = s ? W16 : W8;
            const int H_ = s ? H16 : H8;
            const float* __restrict__ relm =
                (s ? rel16 : rel8) + (size_t)b * (s ? P16 : P8);
            const __half* __restrict__ ft =
                (s ? ft16 : ft8) + (size_t)b * (s ? P16 : P8) * C;

            const float ix = ((gx + 1.0f) * W_ - 1.0f) * 0.5f;
            const float iy = ((gy + 1.0f) * H_ - 1.0f) * 0.5f;
            const float x0f = floorf(ix), y0f = floorf(iy);
            const int x0 = (int)x0f, y0 = (int)y0f;
            const int x1 = x0 + 1, y1 = y0 + 1;
            const float fx1 = ix - x0f, fx0 = 1.0f - fx1;
            const float fy1 = iy - y0f, fy0 = 1.0f - fy1;
            const bool vx0 = (x0 >= 0) && (x0 < W_);
            const bool vx1 = (x1 >= 0) && (x1 < W_);
            const bool vy0 = (y0 >= 0) && (y0 < H_);
            const bool vy1 = (y1 >= 0) && (y1 < H_);
            const float w00 = (vx0 && vy0) ? fx0 * fy0 : 0.0f;
            const float w10 = (vx1 && vy0) ? fx1 * fy0 : 0.0f;
            const float w01 = (vx0 && vy1) ? fx0 * fy1 : 0.0f;
            const float w11 = (vx1 && vy1) ? fx1 * fy1 : 0.0f;
            const int cx0 = min(max(x0, 0), W_ - 1);
            const int cx1 = min(max(x1, 0), W_ - 1);
            const int cy0 = min(max(y0, 0), H_ - 1);
            const int cy1 = min(max(y1, 0), H_ - 1);

            // this lane's row (y0 rows for lanes 0-31, y1 rows for 32-63)
            const int yy = hf ? cy1 : cy0;
            const float wA = hf ? w01 : w00;   // x0 tap weight
            const float wB = hf ? w11 : w10;   // x1 tap weight
            const size_t rb = (size_t)(yy * W_) * C;

            const float4 rA = *reinterpret_cast<const float4*>(ft + rb + (size_t)cx0 * C + cg);
            const float4 rB = *reinterpret_cast<const float4*>(ft + rb + (size_t)cx1 * C + cg);
            float fA[8], fB[8];
            h8_to_f(rA, fA);
            h8_to_f(rB, fB);

            float dot = 0.0f, n2 = 0.0f;
#pragma unroll
            for (int c = 0; c < 8; ++c) {
                const float v = wA * fA[c] + wB * fB[c];
                dot += nf[c] * v;
                n2  += v * v;
            }
#pragma unroll
            for (int off = 32; off; off >>= 1) {
                dot += __shfl_xor(dot, off);
                n2  += __shfl_xor(n2, off);
            }
            if (lane == 0) {
                const float sim = dot * inv_nf / fmaxf(sqrtf(n2), EPS);
                const int p00 = cy0 * W_ + cx0, p10 = cy0 * W_ + cx1;
                const int p01 = cy1 * W_ + cx0, p11 = cy1 * W_ + cx1;
                const float sr = w00 * relm[p00] + w10 * relm[p10]
                               + w01 * relm[p01] + w11 * relm[p11];
                const size_t o = (((size_t)b * K + k) * N + n) * S + s;
                sims[o] = sim;
                rels[o] = wr + sr;
            }
        }
    }
}

// per (b,k): softmax over N*S of rel, weighted sum of sim
__global__ __launch_bounds__(256) void k_logits(
    const float* __restrict__ sims, const float* __restrict__ rels,
    const float* __restrict__ lscale, float* __restrict__ logits)
{
    const int bk = blockIdx.x;
    const int tid = threadIdx.x;
    const int lane = tid & 63, wid = tid >> 6;
    const float* rp = rels + (size_t)bk * (N * S);
    const float* sp = sims + (size_t)bk * (N * S);
    __shared__ float red0[4], red1[4], red2[4];

    float m = -INFINITY;
    for (int i = tid; i < N * S; i += 256) m = fmaxf(m, rp[i]);
#pragma unroll
    for (int off = 32; off; off >>= 1) m = fmaxf(m, __shfl_xor(m, off));
    if (lane == 0) red0[wid] = m;
    __syncthreads();
    m = fmaxf(fmaxf(red0[0], red0[1]), fmaxf(red0[2], red0[3]));

    float se = 0.0f, ss = 0.0f;
    for (int i = tid; i < N * S; i += 256) {
        const float e = expf(rp[i] - m);
        se += e;
        ss += e * sp[i];
    }
#pragma unroll
    for (int off = 32; off; off >>= 1) {
        se += __shfl_xor(se, off);
        ss += __shfl_xor(ss, off);
    }
    if (lane == 0) { red1[wid] = se; red2[wid] = ss; }
    __syncthreads();
    if (tid == 0) {
        const float tse = red1[0] + red1[1] + red1[2] + red1[3];
        const float tss = red2[0] + red2[1] + red2[2] + red2[3];
        logits[bk] = (tss / tse) * expf(lscale[0]);
    }
}

// final softmax over K per b
__global__ __launch_bounds__(64) void k_out(
    const float* __restrict__ logits, float* __restrict__ out)
{
    const int b = blockIdx.x;
    const int lane = threadIdx.x;   // 64
    const float v0 = logits[b * K + lane];
    const float v1 = logits[b * K + lane + 64];
    float m = fmaxf(v0, v1);
#pragma unroll
    for (int off = 32; off; off >>= 1) m = fmaxf(m, __shfl_xor(m, off));
    const float e0 = expf(v0 - m), e1 = expf(v1 - m);
    float se = e0 + e1;
#pragma unroll
    for (int off = 32; off; off >>= 1) se += __shfl_xor(se, off);
    out[b * K + lane] = e0 / se;
    out[b * K + lane + 64] = e1 / se;
}

extern "C" void kernel_launch(void* const* d_in, const int* in_sizes, int n_in,
                              void* d_out, int out_size, void* d_ws, size_t ws_size,
                              hipStream_t stream)
{
    const float* nodew  = (const float*)d_in[0];
    const float* nodef  = (const float*)d_in[1];
    const float* rel8   = (const float*)d_in[2];
    const float* feat8  = (const float*)d_in[3];
    const float* rel16  = (const float*)d_in[4];
    const float* feat16 = (const float*)d_in[5];
    const float* coords = (const float*)d_in[6];
    const float* lscale = (const float*)d_in[7];

    char* ws = (char*)d_ws;
    __half* ft8  = (__half*)ws;                          // B*P8*C fp16
    __half* ft16 = ft8 + (size_t)B * P8 * C;             // B*P16*C fp16
    float* sims   = (float*)(ws + ((size_t)B * (P8 + P16) * C) * sizeof(__half));
    float* rels   = sims + (size_t)B * K * N * S;
    float* logits = rels + (size_t)B * K * N * S;
    float* out    = (float*)d_out;

    hipLaunchKernelGGL(k_transpose, dim3(P8 / 64, C / 64, B), dim3(256), 0, stream,
                       feat8, ft8, P8);
    hipLaunchKernelGGL(k_transpose, dim3(P16 / 64, C / 64, B), dim3(256), 0, stream,
                       feat16, ft16, P16);
    hipLaunchKernelGGL(k_sample, dim3(B * N * WPN / 4), dim3(256), 0, stream,
                       nodew, nodef, rel8, rel16, coords, ft8, ft16, sims, rels);
    hipLaunchKernelGGL(k_logits, dim3(B * K), dim3(256), 0, stream,
                       sims, rels, lscale, logits);
    hipLaunchKernelGGL(k_out, dim3(B), dim3(64), 0, stream, logits, out);
}

// Round 3
// 125.113 us; speedup vs baseline: 2.3670x; 1.2044x over previous
//
#include <hip/hip_runtime.h>
#include <hip/hip_fp16.h>
#include <math.h>

namespace {
constexpr int B = 4, N = 512, K = 128, C = 256, S = 2;
constexpr int H8 = 128, W8 = 128, P8 = H8 * W8;
constexpr int H16 = 64, W16 = 64, P16 = H16 * W16;
constexpr float EPS = 1e-12f;
constexpr int KCH = 8;            // k-samples per wave
constexpr int WPN = K / KCH;      // waves per (b,n) = 16
}

// [B,C,P] fp32 -> [B,P,C] fp16 tiled transpose (64x64 tiles, 256 threads)
__global__ __launch_bounds__(256) void k_transpose(
    const float* __restrict__ in, __half* __restrict__ out, int P)
{
    __shared__ float tile[64][65];
    const int b  = blockIdx.z;
    const int p0 = blockIdx.x * 64;
    const int c0 = blockIdx.y * 64;
    const int tid = threadIdx.x;
    const int tp = tid & 63, tq = tid >> 6;   // tq in 0..3
    const float* src = in + (size_t)b * C * P;
    __half* dst = out + (size_t)b * P * C;
#pragma unroll
    for (int i = 0; i < 16; ++i) {
        const int cl = tq + i * 4;
        tile[cl][tp] = src[(size_t)(c0 + cl) * P + (p0 + tp)];
    }
    __syncthreads();
#pragma unroll
    for (int i = 0; i < 16; ++i) {
        const int pl = tq + i * 4;
        dst[(size_t)(p0 + pl) * C + (c0 + tp)] = __float2half(tile[tp][pl]);
    }
}

__device__ inline void h8_to_f(const float4 r, float* o)
{
    const __half2* h = reinterpret_cast<const __half2*>(&r);
#pragma unroll
    for (int i = 0; i < 4; ++i) {
        const float2 f = __half22float2(h[i]);
        o[2 * i] = f.x; o[2 * i + 1] = f.y;
    }
}

// 4 lane-groups of 16; each group owns one (k, s) sample per iteration.
__global__ __launch_bounds__(256) void k_sample(
    const float* __restrict__ nodew,   // [B,N]
    const float* __restrict__ nodef,   // [B,N,C]
    const float* __restrict__ rel8,    // [B,P8]
    const float* __restrict__ rel16,   // [B,P16]
    const float* __restrict__ coords,  // [B,K,N,2]
    const __half* __restrict__ ft8,    // [B,P8,C]
    const __half* __restrict__ ft16,   // [B,P16,C]
    float* __restrict__ sims,          // [B,K,N,S]
    float* __restrict__ rels)          // [B,K,N,S]
{
    const int wave = blockIdx.x * 4 + (threadIdx.x >> 6);
    const int lane = threadIdx.x & 63;
    const int g    = lane >> 4;        // group 0..3
    const int gl   = lane & 15;        // lane-in-group
    const int cg   = gl * 16;          // 16 channels per lane
    const int b  = wave / (N * WPN);
    const int rr = wave % (N * WPN);
    const int n  = rr / WPN;
    const int kc = rr % WPN;

    // node feature fragment: 16 channels/lane (groups hold identical copies)
    float nf[16];
    {
        const float* np_ = nodef + ((size_t)(b * N + n)) * C + cg;
#pragma unroll
        for (int q = 0; q < 4; ++q) {
            const float4 a = *reinterpret_cast<const float4*>(np_ + 4 * q);
            nf[4*q+0] = a.x; nf[4*q+1] = a.y; nf[4*q+2] = a.z; nf[4*q+3] = a.w;
        }
    }
    float nn = 0.0f;
#pragma unroll
    for (int c = 0; c < 16; ++c) nn += nf[c] * nf[c];
#pragma unroll
    for (int off = 1; off < 16; off <<= 1) nn += __shfl_xor(nn, off);
    const float inv_nf = 1.0f / fmaxf(sqrtf(nn), EPS);
    const float wr = nodew[b * N + n];

#pragma unroll
    for (int it = 0; it < 4; ++it) {
        const int s  = it >> 1;                 // wave-uniform per iteration
        const int kk = (it & 1) * 4 + g;        // group-specific k
        const int k  = kc * KCH + kk;

        const int W_ = s ? W16 : W8;
        const int H_ = s ? H16 : H8;
        const float* __restrict__ relm =
            (s ? rel16 : rel8) + (size_t)b * (s ? P16 : P8);
        const __half* __restrict__ ft =
            (s ? ft16 : ft8) + (size_t)b * (s ? P16 : P8) * C;

        const float gx = coords[(((size_t)b * K + k) * N + n) * 2 + 0];
        const float gy = coords[(((size_t)b * K + k) * N + n) * 2 + 1];

        const float ix = ((gx + 1.0f) * W_ - 1.0f) * 0.5f;
        const float iy = ((gy + 1.0f) * H_ - 1.0f) * 0.5f;
        const float x0f = floorf(ix), y0f = floorf(iy);
        const int x0 = (int)x0f, y0 = (int)y0f;
        const int x1 = x0 + 1, y1 = y0 + 1;
        const float fx1 = ix - x0f, fx0 = 1.0f - fx1;
        const float fy1 = iy - y0f, fy0 = 1.0f - fy1;
        const bool vx0 = (x0 >= 0) && (x0 < W_);
        const bool vx1 = (x1 >= 0) && (x1 < W_);
        const bool vy0 = (y0 >= 0) && (y0 < H_);
        const bool vy1 = (y1 >= 0) && (y1 < H_);
        float w[4];
        w[0] = (vx0 && vy0) ? fx0 * fy0 : 0.0f;
        w[1] = (vx1 && vy0) ? fx1 * fy0 : 0.0f;
        w[2] = (vx0 && vy1) ? fx0 * fy1 : 0.0f;
        w[3] = (vx1 && vy1) ? fx1 * fy1 : 0.0f;
        const int cx0 = min(max(x0, 0), W_ - 1);
        const int cx1 = min(max(x1, 0), W_ - 1);
        const int cy0 = min(max(y0, 0), H_ - 1);
        const int cy1 = min(max(y1, 0), H_ - 1);
        int p[4];
        p[0] = cy0 * W_ + cx0; p[1] = cy0 * W_ + cx1;
        p[2] = cy1 * W_ + cx0; p[3] = cy1 * W_ + cx1;

        float v[16];
#pragma unroll
        for (int c = 0; c < 16; ++c) v[c] = 0.0f;
#pragma unroll
        for (int t = 0; t < 4; ++t) {
            const __half* tp = ft + (size_t)p[t] * C + cg;
            const float4 ra = *reinterpret_cast<const float4*>(tp);
            const float4 rb = *reinterpret_cast<const float4*>(tp + 8);
            float f[16];
            h8_to_f(ra, f);
            h8_to_f(rb, f + 8);
            const float wt = w[t];
#pragma unroll
            for (int c = 0; c < 16; ++c) v[c] += wt * f[c];
        }

        float dot = 0.0f, n2 = 0.0f;
#pragma unroll
        for (int c = 0; c < 16; ++c) {
            dot += nf[c] * v[c];
            n2  += v[c] * v[c];
        }
#pragma unroll
        for (int off = 1; off < 16; off <<= 1) {
            dot += __shfl_xor(dot, off);
            n2  += __shfl_xor(n2, off);
        }
        if (gl == 0) {
            const float sim = dot * inv_nf / fmaxf(sqrtf(n2), EPS);
            const float sr = w[0] * relm[p[0]] + w[1] * relm[p[1]]
                           + w[2] * relm[p[2]] + w[3] * relm[p[3]];
            const size_t o = (((size_t)b * K + k) * N + n) * S + s;
            sims[o] = sim;
            rels[o] = wr + sr;
        }
    }
}

// per (b,k): softmax over N*S of rel, weighted sum of sim
__global__ __launch_bounds__(256) void k_logits(
    const float* __restrict__ sims, const float* __restrict__ rels,
    const float* __restrict__ lscale, float* __restrict__ logits)
{
    const int bk = blockIdx.x;
    const int tid = threadIdx.x;
    const int lane = tid & 63, wid = tid >> 6;
    const float* rp = rels + (size_t)bk * (N * S);
    const float* sp = sims + (size_t)bk * (N * S);
    __shared__ float red0[4], red1[4], red2[4];

    float m = -INFINITY;
    for (int i = tid; i < N * S; i += 256) m = fmaxf(m, rp[i]);
#pragma unroll
    for (int off = 32; off; off >>= 1) m = fmaxf(m, __shfl_xor(m, off));
    if (lane == 0) red0[wid] = m;
    __syncthreads();
    m = fmaxf(fmaxf(red0[0], red0[1]), fmaxf(red0[2], red0[3]));

    float se = 0.0f, ss = 0.0f;
    for (int i = tid; i < N * S; i += 256) {
        const float e = expf(rp[i] - m);
        se += e;
        ss += e * sp[i];
    }
#pragma unroll
    for (int off = 32; off; off >>= 1) {
        se += __shfl_xor(se, off);
        ss += __shfl_xor(ss, off);
    }
    if (lane == 0) { red1[wid] = se; red2[wid] = ss; }
    __syncthreads();
    if (tid == 0) {
        const float tse = red1[0] + red1[1] + red1[2] + red1[3];
        const float tss = red2[0] + red2[1] + red2[2] + red2[3];
        logits[bk] = (tss / tse) * expf(lscale[0]);
    }
}

// final softmax over K per b
__global__ __launch_bounds__(64) void k_out(
    const float* __restrict__ logits, float* __restrict__ out)
{
    const int b = blockIdx.x;
    const int lane = threadIdx.x;   // 64
    const float v0 = logits[b * K + lane];
    const float v1 = logits[b * K + lane + 64];
    float m = fmaxf(v0, v1);
#pragma unroll
    for (int off = 32; off; off >>= 1) m = fmaxf(m, __shfl_xor(m, off));
    const float e0 = expf(v0 - m), e1 = expf(v1 - m);
    float se = e0 + e1;
#pragma unroll
    for (int off = 32; off; off >>= 1) se += __shfl_xor(se, off);
    out[b * K + lane] = e0 / se;
    out[b * K + lane + 64] = e1 / se;
}

extern "C" void kernel_launch(void* const* d_in, const int* in_sizes, int n_in,
                              void* d_out, int out_size, void* d_ws, size_t ws_size,
                              hipStream_t stream)
{
    const float* nodew  = (const float*)d_in[0];
    const float* nodef  = (const float*)d_in[1];
    const float* rel8   = (const float*)d_in[2];
    const float* feat8  = (const float*)d_in[3];
    const float* rel16  = (const float*)d_in[4];
    const float* feat16 = (const float*)d_in[5];
    const float* coords = (const float*)d_in[6];
    const float* lscale = (const float*)d_in[7];

    char* ws = (char*)d_ws;
    __half* ft8  = (__half*)ws;                          // B*P8*C fp16
    __half* ft16 = ft8 + (size_t)B * P8 * C;             // B*P16*C fp16
    float* sims   = (float*)(ws + ((size_t)B * (P8 + P16) * C) * sizeof(__half));
    float* rels   = sims + (size_t)B * K * N * S;
    float* logits = rels + (size_t)B * K * N * S;
    float* out    = (float*)d_out;

    hipLaunchKernelGGL(k_transpose, dim3(P8 / 64, C / 64, B), dim3(256), 0, stream,
                       feat8, ft8, P8);
    hipLaunchKernelGGL(k_transpose, dim3(P16 / 64, C / 64, B), dim3(256), 0, stream,
                       feat16, ft16, P16);
    hipLaunchKernelGGL(k_sample, dim3(B * N * WPN / 4), dim3(256), 0, stream,
                       nodew, nodef, rel8, rel16, coords, ft8, ft16, sims, rels);
    hipLaunchKernelGGL(k_logits, dim3(B * K), dim3(256), 0, stream,
                       sims, rels, lscale, logits);
    hipLaunchKernelGGL(k_out, dim3(B), dim3(64), 0, stream, logits, out);
}

// Round 4
// 117.512 us; speedup vs baseline: 2.5201x; 1.0647x over previous
//
#include <hip/hip_runtime.h>
#include <math.h>

typedef _Float16 f16;
typedef _Float16 f16x2 __attribute__((ext_vector_type(2)));

namespace {
constexpr int B = 4, N = 512, K = 128, C = 256, S = 2;
constexpr int H8 = 128, W8 = 128, P8 = H8 * W8;
constexpr int H16 = 64, W16 = 64, P16 = H16 * W16;
constexpr float EPS = 1e-12f;
constexpr int KCH = 8;            // k-samples per wave
constexpr int WPN = K / KCH;      // waves per (b,n) = 16
}

__device__ __forceinline__ float fdot2a(f16x2 a, f16x2 b, float c)
{
#if __has_builtin(__builtin_amdgcn_fdot2)
    return __builtin_amdgcn_fdot2(a, b, c, false);
#else
    return c + (float)a.x * (float)b.x + (float)a.y * (float)b.y;
#endif
}

// [B,C,P] fp32 -> [B,P,C] fp16 tiled transpose (64x64 tiles, 256 threads)
__global__ __launch_bounds__(256) void k_transpose(
    const float* __restrict__ in, f16* __restrict__ out, int P)
{
    __shared__ float tile[64][65];
    const int b  = blockIdx.z;
    const int p0 = blockIdx.x * 64;
    const int c0 = blockIdx.y * 64;
    const int tid = threadIdx.x;
    const int tp = tid & 63, tq = tid >> 6;   // tq in 0..3
    const float* src = in + (size_t)b * C * P;
    f16* dst = out + (size_t)b * P * C;
#pragma unroll
    for (int i = 0; i < 16; ++i) {
        const int cl = tq + i * 4;
        tile[cl][tp] = src[(size_t)(c0 + cl) * P + (p0 + tp)];
    }
    __syncthreads();
#pragma unroll
    for (int i = 0; i < 16; ++i) {
        const int pl = tq + i * 4;
        dst[(size_t)(p0 + pl) * C + (c0 + tp)] = (f16)tile[tp][pl];
    }
}

// 4 lane-groups of 16; each group owns one (k, s) sample per iteration.
__global__ __launch_bounds__(256) void k_sample(
    const float* __restrict__ nodew,   // [B,N]
    const float* __restrict__ nodef,   // [B,N,C]
    const float* __restrict__ rel8,    // [B,P8]
    const float* __restrict__ rel16,   // [B,P16]
    const float* __restrict__ coords,  // [B,K,N,2]
    const f16* __restrict__ ft8,       // [B,P8,C]
    const f16* __restrict__ ft16,      // [B,P16,C]
    float* __restrict__ sims,          // [B,K,N,S]
    float* __restrict__ rels)          // [B,K,N,S]
{
    const int wave = blockIdx.x * 4 + (threadIdx.x >> 6);
    const int lane = threadIdx.x & 63;
    const int g    = lane >> 4;        // group 0..3
    const int gl   = lane & 15;        // lane-in-group
    const int cg   = gl * 16;          // 16 channels per lane
    const int b  = wave / (N * WPN);
    const int rr = wave % (N * WPN);
    const int n  = rr / WPN;
    const int kc = rr % WPN;

    // node feature fragment, fp16 pairs (16 ch/lane)
    f16x2 nf2[8];
    {
        const float* np_ = nodef + ((size_t)(b * N + n)) * C + cg;
#pragma unroll
        for (int q = 0; q < 4; ++q) {
            const float4 a = *reinterpret_cast<const float4*>(np_ + 4 * q);
            nf2[2*q]   = f16x2{(f16)a.x, (f16)a.y};
            nf2[2*q+1] = f16x2{(f16)a.z, (f16)a.w};
        }
    }
    float nn = 0.0f;
#pragma unroll
    for (int c = 0; c < 8; ++c) nn = fdot2a(nf2[c], nf2[c], nn);
#pragma unroll
    for (int off = 1; off < 16; off <<= 1) nn += __shfl_xor(nn, off);
    const float inv_nf = 1.0f / fmaxf(sqrtf(nn), EPS);
    const float wr = nodew[b * N + n];

    // ---- precompute all 4 iterations: tap offsets, weights, rel blends ----
    int   pp[4][4];
    f16x2 ww[4][4];
    float srv[4];
#pragma unroll
    for (int it = 0; it < 4; ++it) {
        const int s  = it >> 1;
        const int k  = kc * KCH + (it & 1) * 4 + g;
        const int W_ = s ? W16 : W8;
        const int H_ = s ? H16 : H8;
        const float* __restrict__ relm =
            (s ? rel16 : rel8) + (size_t)b * (s ? P16 : P8);
        const float gx = coords[(((size_t)b * K + k) * N + n) * 2 + 0];
        const float gy = coords[(((size_t)b * K + k) * N + n) * 2 + 1];
        const float ix = ((gx + 1.0f) * W_ - 1.0f) * 0.5f;
        const float iy = ((gy + 1.0f) * H_ - 1.0f) * 0.5f;
        const float x0f = floorf(ix), y0f = floorf(iy);
        const int x0 = (int)x0f, y0 = (int)y0f;
        const int x1 = x0 + 1, y1 = y0 + 1;
        const float fx1 = ix - x0f, fx0 = 1.0f - fx1;
        const float fy1 = iy - y0f, fy0 = 1.0f - fy1;
        const bool vx0 = (x0 >= 0) && (x0 < W_);
        const bool vx1 = (x1 >= 0) && (x1 < W_);
        const bool vy0 = (y0 >= 0) && (y0 < H_);
        const bool vy1 = (y1 >= 0) && (y1 < H_);
        float w[4];
        w[0] = (vx0 && vy0) ? fx0 * fy0 : 0.0f;
        w[1] = (vx1 && vy0) ? fx1 * fy0 : 0.0f;
        w[2] = (vx0 && vy1) ? fx0 * fy1 : 0.0f;
        w[3] = (vx1 && vy1) ? fx1 * fy1 : 0.0f;
        const int cx0 = min(max(x0, 0), W_ - 1);
        const int cx1 = min(max(x1, 0), W_ - 1);
        const int cy0 = min(max(y0, 0), H_ - 1);
        const int cy1 = min(max(y1, 0), H_ - 1);
        pp[it][0] = cy0 * W_ + cx0; pp[it][1] = cy0 * W_ + cx1;
        pp[it][2] = cy1 * W_ + cx0; pp[it][3] = cy1 * W_ + cx1;
        srv[it] = w[0] * relm[pp[it][0]] + w[1] * relm[pp[it][1]]
                + w[2] * relm[pp[it][2]] + w[3] * relm[pp[it][3]];
#pragma unroll
        for (int t = 0; t < 4; ++t) {
            const f16 h = (f16)w[t];
            ww[it][t] = f16x2{h, h};
        }
    }

    // ---- compute: packed fp16 blend + dot2 ----
#pragma unroll
    for (int it = 0; it < 4; ++it) {
        const int s = it >> 1;
        const f16* __restrict__ ft =
            (s ? ft16 : ft8) + (size_t)b * (s ? P16 : P8) * C;

        float4 ra[4], rb[4];
#pragma unroll
        for (int t = 0; t < 4; ++t) {
            const f16* tp = ft + (size_t)pp[it][t] * C + cg;
            ra[t] = *reinterpret_cast<const float4*>(tp);
            rb[t] = *reinterpret_cast<const float4*>(tp + 8);
        }

        f16x2 v[8];
        {
            const f16x2* a0 = reinterpret_cast<const f16x2*>(&ra[0]);
            const f16x2* b0 = reinterpret_cast<const f16x2*>(&rb[0]);
#pragma unroll
            for (int c = 0; c < 4; ++c) {
                v[c]     = ww[it][0] * a0[c];
                v[c + 4] = ww[it][0] * b0[c];
            }
        }
#pragma unroll
        for (int t = 1; t < 4; ++t) {
            const f16x2* at = reinterpret_cast<const f16x2*>(&ra[t]);
            const f16x2* bt = reinterpret_cast<const f16x2*>(&rb[t]);
#pragma unroll
            for (int c = 0; c < 4; ++c) {
                v[c]     += ww[it][t] * at[c];
                v[c + 4] += ww[it][t] * bt[c];
            }
        }

        float dot = 0.0f, n2 = 0.0f;
#pragma unroll
        for (int c = 0; c < 8; ++c) {
            dot = fdot2a(nf2[c], v[c], dot);
            n2  = fdot2a(v[c], v[c], n2);
        }
#pragma unroll
        for (int off = 1; off < 16; off <<= 1) {
            dot += __shfl_xor(dot, off);
            n2  += __shfl_xor(n2, off);
        }
        if (gl == 0) {
            const int k = kc * KCH + (it & 1) * 4 + g;
            const float sim = dot * inv_nf / fmaxf(sqrtf(n2), EPS);
            const size_t o = (((size_t)b * K + k) * N + n) * S + s;
            sims[o] = sim;
            rels[o] = wr + srv[it];
        }
    }
}

// per (b,k): softmax over N*S of rel, weighted sum of sim
__global__ __launch_bounds__(256) void k_logits(
    const float* __restrict__ sims, const float* __restrict__ rels,
    const float* __restrict__ lscale, float* __restrict__ logits)
{
    const int bk = blockIdx.x;
    const int tid = threadIdx.x;
    const int lane = tid & 63, wid = tid >> 6;
    const float* rp = rels + (size_t)bk * (N * S);
    const float* sp = sims + (size_t)bk * (N * S);
    __shared__ float red0[4], red1[4], red2[4];

    float m = -INFINITY;
    for (int i = tid; i < N * S; i += 256) m = fmaxf(m, rp[i]);
#pragma unroll
    for (int off = 32; off; off >>= 1) m = fmaxf(m, __shfl_xor(m, off));
    if (lane == 0) red0[wid] = m;
    __syncthreads();
    m = fmaxf(fmaxf(red0[0], red0[1]), fmaxf(red0[2], red0[3]));

    float se = 0.0f, ss = 0.0f;
    for (int i = tid; i < N * S; i += 256) {
        const float e = expf(rp[i] - m);
        se += e;
        ss += e * sp[i];
    }
#pragma unroll
    for (int off = 32; off; off >>= 1) {
        se += __shfl_xor(se, off);
        ss += __shfl_xor(ss, off);
    }
    if (lane == 0) { red1[wid] = se; red2[wid] = ss; }
    __syncthreads();
    if (tid == 0) {
        const float tse = red1[0] + red1[1] + red1[2] + red1[3];
        const float tss = red2[0] + red2[1] + red2[2] + red2[3];
        logits[bk] = (tss / tse) * expf(lscale[0]);
    }
}

// final softmax over K per b
__global__ __launch_bounds__(64) void k_out(
    const float* __restrict__ logits, float* __restrict__ out)
{
    const int b = blockIdx.x;
    const int lane = threadIdx.x;   // 64
    const float v0 = logits[b * K + lane];
    const float v1 = logits[b * K + lane + 64];
    float m = fmaxf(v0, v1);
#pragma unroll
    for (int off = 32; off; off >>= 1) m = fmaxf(m, __shfl_xor(m, off));
    const float e0 = expf(v0 - m), e1 = expf(v1 - m);
    float se = e0 + e1;
#pragma unroll
    for (int off = 32; off; off >>= 1) se += __shfl_xor(se, off);
    out[b * K + lane] = e0 / se;
    out[b * K + lane + 64] = e1 / se;
}

extern "C" void kernel_launch(void* const* d_in, const int* in_sizes, int n_in,
                              void* d_out, int out_size, void* d_ws, size_t ws_size,
                              hipStream_t stream)
{
    const float* nodew  = (const float*)d_in[0];
    const float* nodef  = (const float*)d_in[1];
    const float* rel8   = (const float*)d_in[2];
    const float* feat8  = (const float*)d_in[3];
    const float* rel16  = (const float*)d_in[4];
    const float* feat16 = (const float*)d_in[5];
    const float* coords = (const float*)d_in[6];
    const float* lscale = (const float*)d_in[7];

    char* ws = (char*)d_ws;
    f16* ft8  = (f16*)ws;                                // B*P8*C fp16
    f16* ft16 = ft8 + (size_t)B * P8 * C;                // B*P16*C fp16
    float* sims   = (float*)(ws + ((size_t)B * (P8 + P16) * C) * sizeof(f16));
    float* rels   = sims + (size_t)B * K * N * S;
    float* logits = rels + (size_t)B * K * N * S;
    float* out    = (float*)d_out;

    hipLaunchKernelGGL(k_transpose, dim3(P8 / 64, C / 64, B), dim3(256), 0, stream,
                       feat8, ft8, P8);
    hipLaunchKernelGGL(k_transpose, dim3(P16 / 64, C / 64, B), dim3(256), 0, stream,
                       feat16, ft16, P16);
    hipLaunchKernelGGL(k_sample, dim3(B * N * WPN / 4), dim3(256), 0, stream,
                       nodew, nodef, rel8, rel16, coords, ft8, ft16, sims, rels);
    hipLaunchKernelGGL(k_logits, dim3(B * K), dim3(256), 0, stream,
                       sims, rels, lscale, logits);
    hipLaunchKernelGGL(k_out, dim3(B), dim3(64), 0, stream, logits, out);
}

// Round 5
// 115.572 us; speedup vs baseline: 2.5624x; 1.0168x over previous
//
#include <hip/hip_runtime.h>
#include <math.h>

typedef _Float16 f16;
typedef _Float16 f16x2 __attribute__((ext_vector_type(2)));

namespace {
constexpr int B = 4, N = 512, K = 128, C = 256, S = 2;
constexpr int H8 = 128, W8 = 128, P8 = H8 * W8;
constexpr int H16 = 64, W16 = 64, P16 = H16 * W16;
constexpr float EPS = 1e-12f;
constexpr int KCH = 8;            // k-samples per wave
constexpr int WPN = K / KCH;      // waves per (b,n) = 16
}

__device__ __forceinline__ float fdot2a(f16x2 a, f16x2 b, float c)
{
#if __has_builtin(__builtin_amdgcn_fdot2)
    return __builtin_amdgcn_fdot2(a, b, c, false);
#else
    return c + (float)a.x * (float)b.x + (float)a.y * (float)b.y;
#endif
}

// 16-lane (DPP row) sum reduction, pure VALU pipe: xor1, xor2, half-mirror, mirror
__device__ __forceinline__ float red16_sum(float x)
{
    int t;
    t = __builtin_amdgcn_update_dpp(0, __float_as_int(x), 0xB1,  0xF, 0xF, true);
    x += __int_as_float(t);
    t = __builtin_amdgcn_update_dpp(0, __float_as_int(x), 0x4E,  0xF, 0xF, true);
    x += __int_as_float(t);
    t = __builtin_amdgcn_update_dpp(0, __float_as_int(x), 0x141, 0xF, 0xF, true);
    x += __int_as_float(t);
    t = __builtin_amdgcn_update_dpp(0, __float_as_int(x), 0x140, 0xF, 0xF, true);
    x += __int_as_float(t);
    return x;
}

// [B,C,P] fp32 -> [B,P,C] fp16 tiled transpose (64x64 tiles, 256 threads)
__global__ __launch_bounds__(256) void k_transpose(
    const float* __restrict__ in, f16* __restrict__ out, int P)
{
    __shared__ float tile[64][65];
    const int b  = blockIdx.z;
    const int p0 = blockIdx.x * 64;
    const int c0 = blockIdx.y * 64;
    const int tid = threadIdx.x;
    const int tp = tid & 63, tq = tid >> 6;   // tq in 0..3
    const float* src = in + (size_t)b * C * P;
    f16* dst = out + (size_t)b * P * C;
#pragma unroll
    for (int i = 0; i < 16; ++i) {
        const int cl = tq + i * 4;
        tile[cl][tp] = src[(size_t)(c0 + cl) * P + (p0 + tp)];
    }
    __syncthreads();
#pragma unroll
    for (int i = 0; i < 16; ++i) {
        const int pl = tq + i * 4;
        dst[(size_t)(p0 + pl) * C + (c0 + tp)] = (f16)tile[tp][pl];
    }
}

// 4 lane-groups of 16; each group owns one (k, s) sample per iteration.
__global__ __launch_bounds__(256) void k_sample(
    const float* __restrict__ nodew,   // [B,N]
    const float* __restrict__ nodef,   // [B,N,C]
    const float* __restrict__ rel8,    // [B,P8]
    const float* __restrict__ rel16,   // [B,P16]
    const float* __restrict__ coords,  // [B,K,N,2]
    const f16* __restrict__ ft8,       // [B,P8,C]
    const f16* __restrict__ ft16,      // [B,P16,C]
    float* __restrict__ sims,          // [B,K,N,S]
    float* __restrict__ rels)          // [B,K,N,S]
{
    const int wave = blockIdx.x * 4 + (threadIdx.x >> 6);
    const int lane = threadIdx.x & 63;
    const int g    = lane >> 4;        // group 0..3
    const int gl   = lane & 15;        // lane-in-group
    const int cg   = gl * 16;          // 16 channels per lane
    const int b  = wave / (N * WPN);
    const int rr = wave % (N * WPN);
    const int n  = rr / WPN;
    const int kc = rr % WPN;

    // node feature fragment, fp16 pairs (16 ch/lane)
    f16x2 nf2[8];
    {
        const float* np_ = nodef + ((size_t)(b * N + n)) * C + cg;
#pragma unroll
        for (int q = 0; q < 4; ++q) {
            const float4 a = *reinterpret_cast<const float4*>(np_ + 4 * q);
            nf2[2*q]   = f16x2{(f16)a.x, (f16)a.y};
            nf2[2*q+1] = f16x2{(f16)a.z, (f16)a.w};
        }
    }
    float nn = 0.0f;
#pragma unroll
    for (int c = 0; c < 8; ++c) nn = fdot2a(nf2[c], nf2[c], nn);
    nn = red16_sum(nn);
    const float inv_nf = __frsqrt_rn(fmaxf(nn, 1e-24f));
    const float wr = nodew[b * N + n];

    // ---- precompute all 4 iterations: tap offsets, weights, rel blends ----
    int   pp[4][4];
    f16x2 ww[4][4];
    float srv[4];
#pragma unroll
    for (int it = 0; it < 4; ++it) {
        const int s  = it >> 1;
        const int k  = kc * KCH + (it & 1) * 4 + g;
        const int W_ = s ? W16 : W8;
        const int H_ = s ? H16 : H8;
        const float* __restrict__ relm =
            (s ? rel16 : rel8) + (size_t)b * (s ? P16 : P8);
        const float gx = coords[(((size_t)b * K + k) * N + n) * 2 + 0];
        const float gy = coords[(((size_t)b * K + k) * N + n) * 2 + 1];
        const float ix = ((gx + 1.0f) * W_ - 1.0f) * 0.5f;
        const float iy = ((gy + 1.0f) * H_ - 1.0f) * 0.5f;
        const float x0f = floorf(ix), y0f = floorf(iy);
        const int x0 = (int)x0f, y0 = (int)y0f;
        const int x1 = x0 + 1, y1 = y0 + 1;
        const float fx1 = ix - x0f, fx0 = 1.0f - fx1;
        const float fy1 = iy - y0f, fy0 = 1.0f - fy1;
        const bool vx0 = (x0 >= 0) && (x0 < W_);
        const bool vx1 = (x1 >= 0) && (x1 < W_);
        const bool vy0 = (y0 >= 0) && (y0 < H_);
        const bool vy1 = (y1 >= 0) && (y1 < H_);
        float w[4];
        w[0] = (vx0 && vy0) ? fx0 * fy0 : 0.0f;
        w[1] = (vx1 && vy0) ? fx1 * fy0 : 0.0f;
        w[2] = (vx0 && vy1) ? fx0 * fy1 : 0.0f;
        w[3] = (vx1 && vy1) ? fx1 * fy1 : 0.0f;
        const int cx0 = min(max(x0, 0), W_ - 1);
        const int cx1 = min(max(x1, 0), W_ - 1);
        const int cy0 = min(max(y0, 0), H_ - 1);
        const int cy1 = min(max(y1, 0), H_ - 1);
        pp[it][0] = cy0 * W_ + cx0; pp[it][1] = cy0 * W_ + cx1;
        pp[it][2] = cy1 * W_ + cx0; pp[it][3] = cy1 * W_ + cx1;
        srv[it] = w[0] * relm[pp[it][0]] + w[1] * relm[pp[it][1]]
                + w[2] * relm[pp[it][2]] + w[3] * relm[pp[it][3]];
#pragma unroll
        for (int t = 0; t < 4; ++t) {
            const f16 h = (f16)w[t];
            ww[it][t] = f16x2{h, h};
        }
    }

    const f16* __restrict__ fbase[2] = {
        ft8  + (size_t)b * P8  * C,
        ft16 + (size_t)b * P16 * C
    };

    // ---- depth-2 pipelined compute: load it+1 while computing it ----
    float4 ra[2][4], rb[2][4];   // [buf][tap]
#pragma unroll
    for (int t = 0; t < 4; ++t) {
        const f16* tp = fbase[0] + (size_t)pp[0][t] * C + cg;
        ra[0][t] = *reinterpret_cast<const float4*>(tp);
        rb[0][t] = *reinterpret_cast<const float4*>(tp + 8);
    }

#pragma unroll
    for (int it = 0; it < 4; ++it) {
        const int cur = it & 1, nxt = cur ^ 1;
        if (it < 3) {
            const f16* __restrict__ fb = fbase[(it + 1) >> 1];
#pragma unroll
            for (int t = 0; t < 4; ++t) {
                const f16* tp = fb + (size_t)pp[it + 1][t] * C + cg;
                ra[nxt][t] = *reinterpret_cast<const float4*>(tp);
                rb[nxt][t] = *reinterpret_cast<const float4*>(tp + 8);
            }
        }

        f16x2 v[8];
        {
            const f16x2* a0 = reinterpret_cast<const f16x2*>(&ra[cur][0]);
            const f16x2* b0 = reinterpret_cast<const f16x2*>(&rb[cur][0]);
#pragma unroll
            for (int c = 0; c < 4; ++c) {
                v[c]     = ww[it][0] * a0[c];
                v[c + 4] = ww[it][0] * b0[c];
            }
        }
#pragma unroll
        for (int t = 1; t < 4; ++t) {
            const f16x2* at = reinterpret_cast<const f16x2*>(&ra[cur][t]);
            const f16x2* bt = reinterpret_cast<const f16x2*>(&rb[cur][t]);
#pragma unroll
            for (int c = 0; c < 4; ++c) {
                v[c]     += ww[it][t] * at[c];
                v[c + 4] += ww[it][t] * bt[c];
            }
        }

        float dot = 0.0f, n2 = 0.0f;
#pragma unroll
        for (int c = 0; c < 8; ++c) {
            dot = fdot2a(nf2[c], v[c], dot);
            n2  = fdot2a(v[c], v[c], n2);
        }
        dot = red16_sum(dot);
        n2  = red16_sum(n2);

        if (gl == 0) {
            const int s = it >> 1;
            const int k = kc * KCH + (it & 1) * 4 + g;
            const float sim = dot * inv_nf * __frsqrt_rn(fmaxf(n2, 1e-24f));
            const size_t o = (((size_t)b * K + k) * N + n) * S + s;
            sims[o] = sim;
            rels[o] = wr + srv[it];
        }
    }
}

// per (b,k): softmax over N*S of rel, weighted sum of sim
__global__ __launch_bounds__(256) void k_logits(
    const float* __restrict__ sims, const float* __restrict__ rels,
    const float* __restrict__ lscale, float* __restrict__ logits)
{
    const int bk = blockIdx.x;
    const int tid = threadIdx.x;
    const int lane = tid & 63, wid = tid >> 6;
    const float* rp = rels + (size_t)bk * (N * S);
    const float* sp = sims + (size_t)bk * (N * S);
    __shared__ float red0[4], red1[4], red2[4];

    float m = -INFINITY;
    for (int i = tid; i < N * S; i += 256) m = fmaxf(m, rp[i]);
#pragma unroll
    for (int off = 32; off; off >>= 1) m = fmaxf(m, __shfl_xor(m, off));
    if (lane == 0) red0[wid] = m;
    __syncthreads();
    m = fmaxf(fmaxf(red0[0], red0[1]), fmaxf(red0[2], red0[3]));

    float se = 0.0f, ss = 0.0f;
    for (int i = tid; i < N * S; i += 256) {
        const float e = expf(rp[i] - m);
        se += e;
        ss += e * sp[i];
    }
#pragma unroll
    for (int off = 32; off; off >>= 1) {
        se += __shfl_xor(se, off);
        ss += __shfl_xor(ss, off);
    }
    if (lane == 0) { red1[wid] = se; red2[wid] = ss; }
    __syncthreads();
    if (tid == 0) {
        const float tse = red1[0] + red1[1] + red1[2] + red1[3];
        const float tss = red2[0] + red2[1] + red2[2] + red2[3];
        logits[bk] = (tss / tse) * expf(lscale[0]);
    }
}

// final softmax over K per b
__global__ __launch_bounds__(64) void k_out(
    const float* __restrict__ logits, float* __restrict__ out)
{
    const int b = blockIdx.x;
    const int lane = threadIdx.x;   // 64
    const float v0 = logits[b * K + lane];
    const float v1 = logits[b * K + lane + 64];
    float m = fmaxf(v0, v1);
#pragma unroll
    for (int off = 32; off; off >>= 1) m = fmaxf(m, __shfl_xor(m, off));
    const float e0 = expf(v0 - m), e1 = expf(v1 - m);
    float se = e0 + e1;
#pragma unroll
    for (int off = 32; off; off >>= 1) se += __shfl_xor(se, off);
    out[b * K + lane] = e0 / se;
    out[b * K + lane + 64] = e1 / se;
}

extern "C" void kernel_launch(void* const* d_in, const int* in_sizes, int n_in,
                              void* d_out, int out_size, void* d_ws, size_t ws_size,
                              hipStream_t stream)
{
    const float* nodew  = (const float*)d_in[0];
    const float* nodef  = (const float*)d_in[1];
    const float* rel8   = (const float*)d_in[2];
    const float* feat8  = (const float*)d_in[3];
    const float* rel16  = (const float*)d_in[4];
    const float* feat16 = (const float*)d_in[5];
    const float* coords = (const float*)d_in[6];
    const float* lscale = (const float*)d_in[7];

    char* ws = (char*)d_ws;
    f16* ft8  = (f16*)ws;                                // B*P8*C fp16
    f16* ft16 = ft8 + (size_t)B * P8 * C;                // B*P16*C fp16
    float* sims   = (float*)(ws + ((size_t)B * (P8 + P16) * C) * sizeof(f16));
    float* rels   = sims + (size_t)B * K * N * S;
    float* logits = rels + (size_t)B * K * N * S;
    float* out    = (float*)d_out;

    hipLaunchKernelGGL(k_transpose, dim3(P8 / 64, C / 64, B), dim3(256), 0, stream,
                       feat8, ft8, P8);
    hipLaunchKernelGGL(k_transpose, dim3(P16 / 64, C / 64, B), dim3(256), 0, stream,
                       feat16, ft16, P16);
    hipLaunchKernelGGL(k_sample, dim3(B * N * WPN / 4), dim3(256), 0, stream,
                       nodew, nodef, rel8, rel16, coords, ft8, ft16, sims, rels);
    hipLaunchKernelGGL(k_logits, dim3(B * K), dim3(256), 0, stream,
                       sims, rels, lscale, logits);
    hipLaunchKernelGGL(k_out, dim3(B), dim3(64), 0, stream, logits, out);
}